// Round 22
// baseline (96.056 us; speedup 1.0000x reference)
//
#include <hip/hip_runtime.h>
#include <hip/hip_bf16.h>

#define BB 4
#define CC 128
#define NN 4096
#define CK 32
#define L2E 1.442695040888963f

typedef __attribute__((ext_vector_type(8))) short short8v;
typedef __attribute__((ext_vector_type(4))) float float4v;

__device__ inline ushort f2bf(float f) {
    union { __hip_bfloat16 h; ushort u; } cv;
    cv.h = __float2bfloat16(f);
    return cv.u;
}
__device__ inline float bf2f(ushort u) {
    union { uint u; float f; } cv;
    cv.u = ((uint)u) << 16;
    return cv.f;
}
__device__ inline uint pk2(float lo, float hi) {
    return ((uint)f2bf(lo)) | ((uint)f2bf(hi) << 16);
}
__device__ __forceinline__ void gll16(const void* g, void* l) {
    __builtin_amdgcn_global_load_lds(
        (const __attribute__((address_space(1))) void*)g,
        (__attribute__((address_space(3))) void*)l, 16, 0, 0);
}

// ---------------------------------------------------------------------------
// Kernel 0: weight prep.  Wcat[192][128] bf16 = {Wf*L2E; Wg; Wh*sgn},
// bias[192] fp32 = {bf*L2E; bg; bh*sgn}.
// ---------------------------------------------------------------------------
__global__ __launch_bounds__(512) void wprep_kernel(
    const float* __restrict__ Wf, const float* __restrict__ bf,
    const float* __restrict__ Wg, const float* __restrict__ bg,
    const float* __restrict__ Wh, const float* __restrict__ bh,
    const float* __restrict__ gamma,
    ushort* __restrict__ Wcat, float* __restrict__ bias_cat)
{
    const float sgn = (gamma[0] < 0.f) ? -1.f : 1.f;
    const int t = blockIdx.x * 512 + threadIdx.x;   // 0..24575
    const int o = t >> 7, c = t & 127;
    float w, scale;
    if (o < 32)      { w = Wf[o * 128 + c];        scale = L2E;  }
    else if (o < 64) { w = Wg[(o - 32) * 128 + c]; scale = 1.f;  }
    else             { w = Wh[(o - 64) * 128 + c]; scale = sgn;  }
    Wcat[t] = f2bf(w * scale);
    if (t < 192) {
        const float bv = (t < 32) ? bf[t] * L2E
                       : (t < 64) ? bg[t - 32]
                                  : bh[t - 64] * sgn;
        bias_cat[t] = bv;
    }
}

// ---------------------------------------------------------------------------
// Kernel 1: MFMA projections.  Grid (N/32, B) = 512 blocks, 512 thr.
// ---------------------------------------------------------------------------
__global__ __launch_bounds__(512) void proj_kernel(
    const float* __restrict__ x, const ushort* __restrict__ Wcat,
    const float* __restrict__ bias_cat,
    ushort* __restrict__ ft, ushort* __restrict__ gt, ushort* __restrict__ vh)
{
    __shared__ ushort xs[32][132];
    const int t  = threadIdx.x;
    const int n0 = blockIdx.x * 32;
    const int b  = blockIdx.y;
    const float* xb = x + (size_t)b * CC * NN;

    {
        const int nl = t & 31, cg = t >> 5;
        #pragma unroll
        for (int i = 0; i < 8; ++i) {
            const int c = cg + 16 * i;
            xs[nl][c] = f2bf(xb[(size_t)c * NN + n0 + nl]);
        }
    }
    __syncthreads();

    const int w   = t >> 6;
    const int l   = t & 63;
    const int g16 = l >> 4;
    const int l16 = l & 15;
    const int og  = w >> 1;
    const int nh  = w & 1;

    const float4v zf = {0.f, 0.f, 0.f, 0.f};
    float4v acc[3];
    #pragma unroll
    for (int tt = 0; tt < 3; ++tt) acc[tt] = zf;

    #pragma unroll
    for (int kt = 0; kt < 4; ++kt) {
        const short8v bfr = *reinterpret_cast<const short8v*>(
            &xs[nh * 16 + l16][32 * kt + 8 * g16]);
        #pragma unroll
        for (int tt = 0; tt < 3; ++tt) {
            const short8v afr = *reinterpret_cast<const short8v*>(
                &Wcat[(size_t)(48 * og + 16 * tt + l16) * 128 + 32 * kt + 8 * g16]);
            acc[tt] = __builtin_amdgcn_mfma_f32_16x16x32_bf16(afr, bfr, acc[tt], 0, 0, 0);
        }
    }

    const int n = n0 + nh * 16 + l16;
    #pragma unroll
    for (int tt = 0; tt < 3; ++tt) {
        const int ob = 48 * og + 16 * tt + 4 * g16;
        const float4 b4 = *reinterpret_cast<const float4*>(&bias_cat[ob]);
        const float v0 = acc[tt][0] + b4.x;
        const float v1 = acc[tt][1] + b4.y;
        const float v2 = acc[tt][2] + b4.z;
        const float v3 = acc[tt][3] + b4.w;
        if (ob < 32) {
            ushort4 pk;
            pk.x = f2bf(v0); pk.y = f2bf(v1); pk.z = f2bf(v2); pk.w = f2bf(v3);
            *reinterpret_cast<ushort4*>(&ft[((size_t)b * NN + n) * CK + ob]) = pk;
        } else if (ob < 64) {
            ushort4 pk;
            pk.x = f2bf(v0); pk.y = f2bf(v1); pk.z = f2bf(v2); pk.w = f2bf(v3);
            *reinterpret_cast<ushort4*>(&gt[((size_t)b * NN + n) * CK + (ob - 32)]) = pk;
        } else {
            const int c = ob - 64;
            vh[((size_t)b * CC + c + 0) * NN + n] = f2bf(v0);
            vh[((size_t)b * CC + c + 1) * NN + n] = f2bf(v1);
            vh[((size_t)b * CC + c + 2) * NN + n] = f2bf(v2);
            vh[((size_t)b * CC + c + 3) * NN + n] = f2bf(v3);
        }
    }
}

// ---------------------------------------------------------------------------
// Kernel 2: partial denominators D = sum_m 2^(S~) via MFMA.
// ---------------------------------------------------------------------------
__global__ __launch_bounds__(256) void pass1_kernel(
    const ushort* __restrict__ ft, const ushort* __restrict__ gt,
    float* __restrict__ Dpart)
{
    const int t   = threadIdx.x;
    const int w   = t >> 6;
    const int l   = t & 63;
    const int g16 = l >> 4;
    const int l16 = l & 15;
    const int n0  = blockIdx.x * 64;
    const int b   = blockIdx.y;
    const int mz  = blockIdx.z;

    const ushort* ftb = ft + (size_t)b * NN * CK;
    const ushort* gtb = gt + (size_t)b * NN * CK;

    const short8v afrag = *reinterpret_cast<const short8v*>(
        &ftb[(size_t)(n0 + 16 * w + l16) * CK + 8 * g16]);

    const float4v zf = {0.f, 0.f, 0.f, 0.f};
    float d0 = 0.f, d1 = 0.f, d2 = 0.f, d3 = 0.f;
    const int m0 = mz * 512;

    short8v bfA = *reinterpret_cast<const short8v*>(
        &gtb[(size_t)(m0 + l16) * CK + 8 * g16]);
    #pragma unroll 1
    for (int mt = 0; mt < 32; mt += 2) {
        const short8v bfB = *reinterpret_cast<const short8v*>(
            &gtb[(size_t)(m0 + (mt + 1) * 16 + l16) * CK + 8 * g16]);
        float4v s = __builtin_amdgcn_mfma_f32_16x16x32_bf16(afrag, bfA, zf, 0, 0, 0);
        d0 += __builtin_amdgcn_exp2f(s[0]); d1 += __builtin_amdgcn_exp2f(s[1]);
        d2 += __builtin_amdgcn_exp2f(s[2]); d3 += __builtin_amdgcn_exp2f(s[3]);
        bfA = *reinterpret_cast<const short8v*>(
            &gtb[(size_t)(m0 + (((mt + 2) & 31)) * 16 + l16) * CK + 8 * g16]);
        float4v s2 = __builtin_amdgcn_mfma_f32_16x16x32_bf16(afrag, bfB, zf, 0, 0, 0);
        d0 += __builtin_amdgcn_exp2f(s2[0]); d1 += __builtin_amdgcn_exp2f(s2[1]);
        d2 += __builtin_amdgcn_exp2f(s2[2]); d3 += __builtin_amdgcn_exp2f(s2[3]);
    }
    #pragma unroll
    for (int msk = 1; msk <= 8; msk <<= 1) {
        d0 += __shfl_xor(d0, msk);
        d1 += __shfl_xor(d1, msk);
        d2 += __shfl_xor(d2, msk);
        d3 += __shfl_xor(d3, msk);
    }
    if (l16 < 4) {
        const int n = n0 + 16 * w + 4 * g16 + l16;
        const float v = (l16 == 0) ? d0 : (l16 == 1) ? d1 : (l16 == 2) ? d2 : d3;
        Dpart[((size_t)b * NN + n) * 8 + mz] = v;
    }
}

// ---------------------------------------------------------------------------
// Kernel 3: sc[n] = |gamma| / D[n]
// ---------------------------------------------------------------------------
__global__ __launch_bounds__(256) void reduce_kernel(
    const float* __restrict__ Dpart, float* __restrict__ sc,
    const float* __restrict__ gamma)
{
    const int i = blockIdx.x * 256 + threadIdx.x;
    const float4 a4 = *reinterpret_cast<const float4*>(&Dpart[(size_t)i * 8]);
    const float4 b4 = *reinterpret_cast<const float4*>(&Dpart[(size_t)i * 8 + 4]);
    const float D = (a4.x + a4.y + a4.z + a4.w) + (b4.x + b4.y + b4.z + b4.w);
    sc[i] = fabsf(gamma[0]) / D;
}

// ---------------------------------------------------------------------------
// Kernel 3b: vh[b][c][n] *= sc[b*N + n]
// ---------------------------------------------------------------------------
__global__ __launch_bounds__(256) void vscale_kernel(
    ushort* __restrict__ vh, const float* __restrict__ sc)
{
    const size_t i8   = (size_t)blockIdx.x * 256 + threadIdx.x;
    const size_t base = i8 * 8;
    const int    n    = (int)(base & (NN - 1));
    const int    b    = (int)(base / ((size_t)CC * NN));

    ushort4 v0 = *reinterpret_cast<const ushort4*>(&vh[base]);
    ushort4 v1 = *reinterpret_cast<const ushort4*>(&vh[base + 4]);
    const float4 s0 = *reinterpret_cast<const float4*>(&sc[(size_t)b * NN + n]);
    const float4 s1 = *reinterpret_cast<const float4*>(&sc[(size_t)b * NN + n + 4]);

    v0.x = f2bf(bf2f(v0.x) * s0.x);
    v0.y = f2bf(bf2f(v0.y) * s0.y);
    v0.z = f2bf(bf2f(v0.z) * s0.z);
    v0.w = f2bf(bf2f(v0.w) * s0.w);
    v1.x = f2bf(bf2f(v1.x) * s1.x);
    v1.y = f2bf(bf2f(v1.y) * s1.y);
    v1.z = f2bf(bf2f(v1.z) * s1.z);
    v1.w = f2bf(bf2f(v1.w) * s1.w);

    *reinterpret_cast<ushort4*>(&vh[base])     = v0;
    *reinterpret_cast<ushort4*>(&vh[base + 4]) = v1;
}

// ---------------------------------------------------------------------------
// Kernel 4: sigma-permuted PV with F ALSO staged through LDS (no register-
// destined global loads in the main loop).  F region is per-nq, shared by the
// ch-pair; correctness under sharing via TWO NON-DRAINING s_barriers/step:
//   STAGE(t+1); vmcnt(6); s_barrier   -> everyone's parity-t writes landed
//   compute(parity t)
//   lgkmcnt(0); sched_barrier; s_barrier -> everyone's parity-t reads done
// glls stay in flight across the barriers (T3/T4).  LDS = V 128KB + F 32KB
// = 160KB (1 block/CU, 4 waves/SIMD).  F pre-swizzled (chunk ^ (row&3));
// V even-XOR (chunk ^ (row&6)).
// ---------------------------------------------------------------------------
#define WSTR  8192
#define VBUF  4096
#define FBASE (16 * WSTR)          // 131072
#define FNQ   4096                 // per-nq F region (2 bufs x 2KB)

__global__ __launch_bounds__(1024) void pass2_kernel(
    const ushort* __restrict__ ft, const ushort* __restrict__ gt,
    const ushort* __restrict__ vh,
    const float* __restrict__ x, float* __restrict__ out)
{
    __shared__ __align__(16) char smem[16 * WSTR + 8 * FNQ];   // 160 KB

    const int t   = threadIdx.x;
    const int w   = t >> 6;
    const int l   = t & 63;
    const int g16 = l >> 4;
    const int l16 = l & 15;
    const int ch  = w & 1;     // c-half
    const int nq  = w >> 1;    // n-eighth (0..7)

    const int bid = blockIdx.x;
    const int xcd = bid & 7;
    const int b   = xcd >> 1;
    const int m0  = ((bid >> 3) + 32 * (xcd & 1)) * 64;

    const ushort* ftb = ft + (size_t)b * NN * CK;
    const ushort* gtb = gt + (size_t)b * NN * CK;
    const ushort* vhb = vh + (size_t)b * CC * NN;

    char* wsm = smem + w * WSTR;          // V staging (wave-private)
    char* fsm = smem + FBASE + nq * FNQ;  // F staging (ch-pair shared)

    short8v gfrag[4];
    #pragma unroll
    for (int tm = 0; tm < 4; ++tm)
        gfrag[tm] = *reinterpret_cast<const short8v*>(
            &gtb[(size_t)(m0 + 16 * tm + l16) * CK + 8 * g16]);

    const float4v zf = {0.f, 0.f, 0.f, 0.f};
    float4v acc[4][4];   // [tc][tm]
    #pragma unroll
    for (int tc = 0; tc < 4; ++tc)
        #pragma unroll
        for (int tm = 0; tm < 4; ++tm) acc[tc][tm] = zf;

    const int nbase = nq * 512;
    const int rr = l >> 2, cp = l & 3;
    // F source: lane covers row rr (+16j), chunk cp ^ (rr&3)
    const ushort* fsrc = ftb + (size_t)rr * CK + 8 * (cp ^ (rr & 3));
    // F read offsets (loop-invariant)
    const int fo0 = l16 * 64 + 16 * (g16 ^ (l16 & 3));
    const int fo1 = 1024 + fo0;

#define STAGE(n0_, bo_) do {                                                   \
    _Pragma("unroll")                                                          \
    for (int j = 0; j < 4; ++j) {                                              \
        const int row = j * 16 + rr;                                           \
        gll16(vhb + (size_t)(64 * ch + row) * NN + (n0_)                       \
                  + (((2 * cp) ^ (row & 6)) << 2),                             \
              wsm + (bo_) + j * 1024);                                         \
    }                                                                          \
    _Pragma("unroll")                                                          \
    for (int j = 0; j < 2; ++j)                                                \
        gll16(fsrc + (size_t)((n0_) + 16 * j) * CK,                            \
              fsm + ((bo_) >> 1) + j * 1024);                                  \
} while (0)

    // prologue: stage step 0 (6 glls in flight into loop)
    STAGE(nbase, 0);

    int bo = 0;
    #pragma unroll 1
    for (int st = 0; st < 16; ++st) {
        const int n0 = nbase + st * 32;

        if (st < 15) {
            STAGE(n0 + 32, bo ^ VBUF);
            // keep only the 6 just-issued (parity st+1); parity-st writes done
            asm volatile("s_waitcnt vmcnt(6)" ::: "memory");
        } else {
            asm volatile("s_waitcnt vmcnt(0)" ::: "memory");
        }
        __builtin_amdgcn_s_barrier();   // ALL waves' parity-st writes landed

        const char* Vb = wsm + bo;
        const char* Fb = fsm + (bo >> 1);

        const short8v af0 = *reinterpret_cast<const short8v*>(Fb + fo0);
        const short8v af1 = *reinterpret_cast<const short8v*>(Fb + fo1);

        // S~ = (F*log2e)^T G over 64m x 32n; P = exp2(S~) -> PV B-frags
        union { uint u[4]; short8v s; } pf[4];
        #pragma unroll
        for (int tm = 0; tm < 4; ++tm) {
            float4v s0 = __builtin_amdgcn_mfma_f32_16x16x32_bf16(af0, gfrag[tm], zf, 0, 0, 0);
            float4v s1 = __builtin_amdgcn_mfma_f32_16x16x32_bf16(af1, gfrag[tm], zf, 0, 0, 0);
            pf[tm].u[0] = pk2(__builtin_amdgcn_exp2f(s0[0]), __builtin_amdgcn_exp2f(s0[1]));
            pf[tm].u[1] = pk2(__builtin_amdgcn_exp2f(s0[2]), __builtin_amdgcn_exp2f(s0[3]));
            pf[tm].u[2] = pk2(__builtin_amdgcn_exp2f(s1[0]), __builtin_amdgcn_exp2f(s1[1]));
            pf[tm].u[3] = pk2(__builtin_amdgcn_exp2f(s1[2]), __builtin_amdgcn_exp2f(s1[3]));
        }

        // PV: acc[c,m] += V[c, sigma(k)] * P[sigma(k), m]  (c-half = ch)
        #pragma unroll
        for (int tc = 0; tc < 4; ++tc) {
            const int cl = 16 * tc + l16;
            const uint2 va  = *reinterpret_cast<const uint2*>(
                Vb + cl * 64 + 8 * (g16 ^ (cl & 6)));
            const uint2 vb2 = *reinterpret_cast<const uint2*>(
                Vb + cl * 64 + 8 * ((4 + g16) ^ (cl & 6)));
            union { uint u[4]; short8v s; } av;
            av.u[0] = va.x;  av.u[1] = va.y;
            av.u[2] = vb2.x; av.u[3] = vb2.y;
            #pragma unroll
            for (int tm = 0; tm < 4; ++tm)
                acc[tc][tm] = __builtin_amdgcn_mfma_f32_16x16x32_bf16(av.s, pf[tm].s, acc[tc][tm], 0, 0, 0);
        }

        // all my LDS reads of parity-st complete, then block-wide fence:
        // nobody overwrites parity-st until everyone is done reading it.
        asm volatile("s_waitcnt lgkmcnt(0)" ::: "memory");
        __builtin_amdgcn_sched_barrier(0);
        __builtin_amdgcn_s_barrier();

        bo ^= VBUF;
    }
#undef STAGE

    // ---- epilogue: 3-round cross-nq reduction (staging LDS reused) ----
    float4v* rl = (float4v*)smem;
    __syncthreads();
    if (nq >= 4) {
        const int slot = (nq - 4) * 2 + ch;
        #pragma unroll
        for (int tc = 0; tc < 4; ++tc)
            #pragma unroll
            for (int tm = 0; tm < 4; ++tm)
                rl[(slot * 16 + tc * 4 + tm) * 64 + l] = acc[tc][tm];
    }
    __syncthreads();
    if (nq < 4) {
        const int slot = nq * 2 + ch;
        #pragma unroll
        for (int tc = 0; tc < 4; ++tc)
            #pragma unroll
            for (int tm = 0; tm < 4; ++tm)
                acc[tc][tm] += rl[(slot * 16 + tc * 4 + tm) * 64 + l];
    }
    __syncthreads();
    if (nq == 2 || nq == 3) {
        const int slot = (nq - 2) * 2 + ch;
        #pragma unroll
        for (int tc = 0; tc < 4; ++tc)
            #pragma unroll
            for (int tm = 0; tm < 4; ++tm)
                rl[(slot * 16 + tc * 4 + tm) * 64 + l] = acc[tc][tm];
    }
    __syncthreads();
    if (nq < 2) {
        const int slot = nq * 2 + ch;
        #pragma unroll
        for (int tc = 0; tc < 4; ++tc)
            #pragma unroll
            for (int tm = 0; tm < 4; ++tm)
                acc[tc][tm] += rl[(slot * 16 + tc * 4 + tm) * 64 + l];
    }
    __syncthreads();
    if (nq == 1) {
        #pragma unroll
        for (int tc = 0; tc < 4; ++tc)
            #pragma unroll
            for (int tm = 0; tm < 4; ++tm)
                rl[(ch * 16 + tc * 4 + tm) * 64 + l] = acc[tc][tm];
    }
    __syncthreads();
    if (nq == 0) {
        const float* xb = x   + (size_t)b * CC * NN;
        float*       ob = out + (size_t)b * CC * NN;
        #pragma unroll
        for (int tc = 0; tc < 4; ++tc) {
            #pragma unroll
            for (int tm = 0; tm < 4; ++tm) {
                float4v s = acc[tc][tm] + rl[(ch * 16 + tc * 4 + tm) * 64 + l];
                const int cb = 64 * ch + 16 * tc + 4 * g16;
                const int m  = m0 + 16 * tm + l16;
                #pragma unroll
                for (int r = 0; r < 4; ++r) {
                    const size_t idx = (size_t)(cb + r) * NN + m;
                    ob[idx] = s[r] + xb[idx];
                }
            }
        }
    }
}

// ---------------------------------------------------------------------------
extern "C" void kernel_launch(void* const* d_in, const int* in_sizes, int n_in,
                              void* d_out, int out_size, void* d_ws, size_t ws_size,
                              hipStream_t stream)
{
    const float* x     = (const float*)d_in[0];
    const float* Wf    = (const float*)d_in[1];
    const float* bf    = (const float*)d_in[2];
    const float* Wg    = (const float*)d_in[3];
    const float* bg    = (const float*)d_in[4];
    const float* Wh    = (const float*)d_in[5];
    const float* bh    = (const float*)d_in[6];
    const float* gamma = (const float*)d_in[7];

    ushort* ft = (ushort*)d_ws;                    // [B][N][CK] bf16 (x log2e)
    ushort* gt = ft + (size_t)BB * NN * CK;        // [B][N][CK] bf16
    ushort* vh = gt + (size_t)BB * NN * CK;        // [B][C][N]  bf16 (sign folded)
    float* Dpart = (float*)(vh + (size_t)BB * CC * NN);  // [B*N][8]
    float* sc    = Dpart + (size_t)BB * NN * 8;          // [B*N] |g|/D
    float* bias_cat = sc + (size_t)BB * NN;              // [192]
    ushort* Wcat = (ushort*)(bias_cat + 192);            // [192][128] bf16

    float* out = (float*)d_out;

    wprep_kernel<<<dim3(48), 512, 0, stream>>>(Wf, bf, Wg, bg, Wh, bh, gamma, Wcat, bias_cat);
    proj_kernel<<<dim3(NN / 32, BB), 512, 0, stream>>>(x, Wcat, bias_cat, ft, gt, vh);
    pass1_kernel<<<dim3(NN / 64, BB, 8), 256, 0, stream>>>(ft, gt, Dpart);
    reduce_kernel<<<dim3(BB * NN / 256), 256, 0, stream>>>(Dpart, sc, gamma);
    vscale_kernel<<<dim3(BB * CC * NN / 8 / 256), 256, 0, stream>>>(vh, sc);
    pass2_kernel<<<dim3(256), 1024, 0, stream>>>(ft, gt, vh, x, out);
}

// Round 23
// 88.066 us; speedup vs baseline: 1.0907x; 1.0907x over previous
//
#include <hip/hip_runtime.h>
#include <hip/hip_bf16.h>

#define BB 4
#define CC 128
#define NN 4096
#define CK 32
#define L2E 1.442695040888963f

typedef __attribute__((ext_vector_type(8))) short short8v;
typedef __attribute__((ext_vector_type(4))) float float4v;

__device__ inline ushort f2bf(float f) {
    union { __hip_bfloat16 h; ushort u; } cv;
    cv.h = __float2bfloat16(f);
    return cv.u;
}
__device__ inline uint pk2(float lo, float hi) {
    return ((uint)f2bf(lo)) | ((uint)f2bf(hi) << 16);
}
__device__ __forceinline__ void gll16(const void* g, void* l) {
    __builtin_amdgcn_global_load_lds(
        (const __attribute__((address_space(1))) void*)g,
        (__attribute__((address_space(3))) void*)l, 16, 0, 0);
}

// ---------------------------------------------------------------------------
// Kernel 0: weight prep.  Wcat[192][128] bf16 = {Wf*L2E; Wg; Wh*sgn},
// bias[192] fp32 = {bf*L2E; bg; bh*sgn}.
// ---------------------------------------------------------------------------
__global__ __launch_bounds__(512) void wprep_kernel(
    const float* __restrict__ Wf, const float* __restrict__ bf,
    const float* __restrict__ Wg, const float* __restrict__ bg,
    const float* __restrict__ Wh, const float* __restrict__ bh,
    const float* __restrict__ gamma,
    ushort* __restrict__ Wcat, float* __restrict__ bias_cat)
{
    const float sgn = (gamma[0] < 0.f) ? -1.f : 1.f;
    const int t = blockIdx.x * 512 + threadIdx.x;   // 0..24575
    const int o = t >> 7, c = t & 127;
    float w, scale;
    if (o < 32)      { w = Wf[o * 128 + c];        scale = L2E;  }
    else if (o < 64) { w = Wg[(o - 32) * 128 + c]; scale = 1.f;  }
    else             { w = Wh[(o - 64) * 128 + c]; scale = sgn;  }
    Wcat[t] = f2bf(w * scale);
    if (t < 192) {
        const float bv = (t < 32) ? bf[t] * L2E
                       : (t < 64) ? bg[t - 32]
                                  : bh[t - 64] * sgn;
        bias_cat[t] = bv;
    }
}

// ---------------------------------------------------------------------------
// Kernel 1: MFMA projections.  Grid (N/32, B) = 512 blocks, 512 thr.
// ---------------------------------------------------------------------------
__global__ __launch_bounds__(512) void proj_kernel(
    const float* __restrict__ x, const ushort* __restrict__ Wcat,
    const float* __restrict__ bias_cat,
    ushort* __restrict__ ft, ushort* __restrict__ gt, ushort* __restrict__ vh)
{
    __shared__ ushort xs[32][132];
    const int t  = threadIdx.x;
    const int n0 = blockIdx.x * 32;
    const int b  = blockIdx.y;
    const float* xb = x + (size_t)b * CC * NN;

    {
        const int nl = t & 31, cg = t >> 5;
        #pragma unroll
        for (int i = 0; i < 8; ++i) {
            const int c = cg + 16 * i;
            xs[nl][c] = f2bf(xb[(size_t)c * NN + n0 + nl]);
        }
    }
    __syncthreads();

    const int w   = t >> 6;
    const int l   = t & 63;
    const int g16 = l >> 4;
    const int l16 = l & 15;
    const int og  = w >> 1;
    const int nh  = w & 1;

    const float4v zf = {0.f, 0.f, 0.f, 0.f};
    float4v acc[3];
    #pragma unroll
    for (int tt = 0; tt < 3; ++tt) acc[tt] = zf;

    #pragma unroll
    for (int kt = 0; kt < 4; ++kt) {
        const short8v bfr = *reinterpret_cast<const short8v*>(
            &xs[nh * 16 + l16][32 * kt + 8 * g16]);
        #pragma unroll
        for (int tt = 0; tt < 3; ++tt) {
            const short8v afr = *reinterpret_cast<const short8v*>(
                &Wcat[(size_t)(48 * og + 16 * tt + l16) * 128 + 32 * kt + 8 * g16]);
            acc[tt] = __builtin_amdgcn_mfma_f32_16x16x32_bf16(afr, bfr, acc[tt], 0, 0, 0);
        }
    }

    const int n = n0 + nh * 16 + l16;
    #pragma unroll
    for (int tt = 0; tt < 3; ++tt) {
        const int ob = 48 * og + 16 * tt + 4 * g16;
        const float4 b4 = *reinterpret_cast<const float4*>(&bias_cat[ob]);
        const float v0 = acc[tt][0] + b4.x;
        const float v1 = acc[tt][1] + b4.y;
        const float v2 = acc[tt][2] + b4.z;
        const float v3 = acc[tt][3] + b4.w;
        if (ob < 32) {
            ushort4 pk;
            pk.x = f2bf(v0); pk.y = f2bf(v1); pk.z = f2bf(v2); pk.w = f2bf(v3);
            *reinterpret_cast<ushort4*>(&ft[((size_t)b * NN + n) * CK + ob]) = pk;
        } else if (ob < 64) {
            ushort4 pk;
            pk.x = f2bf(v0); pk.y = f2bf(v1); pk.z = f2bf(v2); pk.w = f2bf(v3);
            *reinterpret_cast<ushort4*>(&gt[((size_t)b * NN + n) * CK + (ob - 32)]) = pk;
        } else {
            const int c = ob - 64;
            vh[((size_t)b * CC + c + 0) * NN + n] = f2bf(v0);
            vh[((size_t)b * CC + c + 1) * NN + n] = f2bf(v1);
            vh[((size_t)b * CC + c + 2) * NN + n] = f2bf(v2);
            vh[((size_t)b * CC + c + 3) * NN + n] = f2bf(v3);
        }
    }
}

// ---------------------------------------------------------------------------
// Kernel 2: partial denominators D = sum_m 2^(S~) via MFMA.
// ---------------------------------------------------------------------------
__global__ __launch_bounds__(256) void pass1_kernel(
    const ushort* __restrict__ ft, const ushort* __restrict__ gt,
    float* __restrict__ Dpart)
{
    const int t   = threadIdx.x;
    const int w   = t >> 6;
    const int l   = t & 63;
    const int g16 = l >> 4;
    const int l16 = l & 15;
    const int n0  = blockIdx.x * 64;
    const int b   = blockIdx.y;
    const int mz  = blockIdx.z;

    const ushort* ftb = ft + (size_t)b * NN * CK;
    const ushort* gtb = gt + (size_t)b * NN * CK;

    const short8v afrag = *reinterpret_cast<const short8v*>(
        &ftb[(size_t)(n0 + 16 * w + l16) * CK + 8 * g16]);

    const float4v zf = {0.f, 0.f, 0.f, 0.f};
    float d0 = 0.f, d1 = 0.f, d2 = 0.f, d3 = 0.f;
    const int m0 = mz * 512;

    short8v bfA = *reinterpret_cast<const short8v*>(
        &gtb[(size_t)(m0 + l16) * CK + 8 * g16]);
    #pragma unroll 1
    for (int mt = 0; mt < 32; mt += 2) {
        const short8v bfB = *reinterpret_cast<const short8v*>(
            &gtb[(size_t)(m0 + (mt + 1) * 16 + l16) * CK + 8 * g16]);
        float4v s = __builtin_amdgcn_mfma_f32_16x16x32_bf16(afrag, bfA, zf, 0, 0, 0);
        d0 += __builtin_amdgcn_exp2f(s[0]); d1 += __builtin_amdgcn_exp2f(s[1]);
        d2 += __builtin_amdgcn_exp2f(s[2]); d3 += __builtin_amdgcn_exp2f(s[3]);
        bfA = *reinterpret_cast<const short8v*>(
            &gtb[(size_t)(m0 + (((mt + 2) & 31)) * 16 + l16) * CK + 8 * g16]);
        float4v s2 = __builtin_amdgcn_mfma_f32_16x16x32_bf16(afrag, bfB, zf, 0, 0, 0);
        d0 += __builtin_amdgcn_exp2f(s2[0]); d1 += __builtin_amdgcn_exp2f(s2[1]);
        d2 += __builtin_amdgcn_exp2f(s2[2]); d3 += __builtin_amdgcn_exp2f(s2[3]);
    }
    #pragma unroll
    for (int msk = 1; msk <= 8; msk <<= 1) {
        d0 += __shfl_xor(d0, msk);
        d1 += __shfl_xor(d1, msk);
        d2 += __shfl_xor(d2, msk);
        d3 += __shfl_xor(d3, msk);
    }
    if (l16 < 4) {
        const int n = n0 + 16 * w + 4 * g16 + l16;
        const float v = (l16 == 0) ? d0 : (l16 == 1) ? d1 : (l16 == 2) ? d2 : d3;
        Dpart[((size_t)b * NN + n) * 8 + mz] = v;
    }
}

// ---------------------------------------------------------------------------
// Kernel 3: sc[n] = |gamma| / D[n]   (applied to P inside pass2)
// ---------------------------------------------------------------------------
__global__ __launch_bounds__(256) void reduce_kernel(
    const float* __restrict__ Dpart, float* __restrict__ sc,
    const float* __restrict__ gamma)
{
    const int i = blockIdx.x * 256 + threadIdx.x;
    const float4 a4 = *reinterpret_cast<const float4*>(&Dpart[(size_t)i * 8]);
    const float4 b4 = *reinterpret_cast<const float4*>(&Dpart[(size_t)i * 8 + 4]);
    const float D = (a4.x + a4.y + a4.z + a4.w) + (b4.x + b4.y + b4.z + b4.w);
    sc[i] = fabsf(gamma[0]) / D;
}

// ---------------------------------------------------------------------------
// Kernel 4 (r16/r19 PROVEN skeleton): sigma-permuted PV.  BM=64, grid 256
// (1 block/CU), 1024 thr = 16 waves = (ch in 2, nq in 8) -> 4 waves/SIMD.
// V staged wave-private dbuf (64c x 32n) via 4 x gll16/step; af + sc direct
// loads issued before STAGE (their drain rides the counted vmcnt(4)); zero
// barriers in main loop.  P = exp2(S~) * sc[n] packed bf16 (vscale deleted).
// ---------------------------------------------------------------------------
#define WSTR  8192
#define VBUF  4096

__global__ __launch_bounds__(1024) void pass2_kernel(
    const ushort* __restrict__ ft, const ushort* __restrict__ gt,
    const ushort* __restrict__ vh, const float* __restrict__ sc,
    const float* __restrict__ x, float* __restrict__ out)
{
    __shared__ __align__(16) char smem[16 * WSTR];   // 128 KB

    const int t   = threadIdx.x;
    const int w   = t >> 6;
    const int l   = t & 63;
    const int g16 = l >> 4;
    const int l16 = l & 15;
    const int ch  = w & 1;     // c-half
    const int nq  = w >> 1;    // n-eighth (0..7)

    const int bid = blockIdx.x;
    const int xcd = bid & 7;
    const int b   = xcd >> 1;
    const int m0  = ((bid >> 3) + 32 * (xcd & 1)) * 64;

    const ushort* ftb = ft + (size_t)b * NN * CK;
    const ushort* gtb = gt + (size_t)b * NN * CK;
    const ushort* vhb = vh + (size_t)b * CC * NN;
    const float*  scb = sc + (size_t)b * NN;

    char* wsm = smem + w * WSTR;

    short8v gfrag[4];
    #pragma unroll
    for (int tm = 0; tm < 4; ++tm)
        gfrag[tm] = *reinterpret_cast<const short8v*>(
            &gtb[(size_t)(m0 + 16 * tm + l16) * CK + 8 * g16]);

    const float4v zf = {0.f, 0.f, 0.f, 0.f};
    float4v acc[4][4];   // [tc][tm]
    #pragma unroll
    for (int tc = 0; tc < 4; ++tc)
        #pragma unroll
        for (int tm = 0; tm < 4; ++tm) acc[tc][tm] = zf;

    const int nbase = nq * 512;
    const int rr = l >> 2, cp = l & 3;

#define STAGE(n0_, bo_) do {                                                   \
    _Pragma("unroll")                                                          \
    for (int j = 0; j < 4; ++j) {                                              \
        const int row = j * 16 + rr;                                           \
        gll16(vhb + (size_t)(64 * ch + row) * NN + (n0_)                       \
                  + (((2 * cp) ^ (row & 6)) << 2),                             \
              wsm + (bo_) + j * 1024);                                         \
    }                                                                          \
} while (0)

    // prologue: stage step 0, drain everything (incl. gfrag loads)
    STAGE(nbase, 0);
    asm volatile("s_waitcnt vmcnt(0)" ::: "memory");

    int bo = 0;
    #pragma unroll 1
    for (int st = 0; st < 16; ++st) {
        const int n0 = nbase + st * 32;

        // af + sc loads for this step (drained by the vmcnt below)
        const short8v af0 = *reinterpret_cast<const short8v*>(
            &ftb[(size_t)(n0 + l16) * CK + 8 * g16]);
        const short8v af1 = *reinterpret_cast<const short8v*>(
            &ftb[(size_t)(n0 + 16 + l16) * CK + 8 * g16]);
        const float4 sc0 = *reinterpret_cast<const float4*>(&scb[n0 + 4 * g16]);
        const float4 sc1 = *reinterpret_cast<const float4*>(&scb[n0 + 16 + 4 * g16]);

        if (st < 15) {
            STAGE(n0 + 32, bo ^ VBUF);
            asm volatile("s_waitcnt vmcnt(4)" ::: "memory");
        } else {
            asm volatile("s_waitcnt vmcnt(0)" ::: "memory");
        }

        const char* Vb = wsm + bo;

        // S~ over 64m x 32n; P = exp2(S~) * sc[n] -> PV B-frags.
        // s0[r] is n-local 4g16+r (sc0); s1[r] is 16+4g16+r (sc1).
        union { uint u[4]; short8v s; } pf[4];
        #pragma unroll
        for (int tm = 0; tm < 4; ++tm) {
            float4v s0 = __builtin_amdgcn_mfma_f32_16x16x32_bf16(af0, gfrag[tm], zf, 0, 0, 0);
            float4v s1 = __builtin_amdgcn_mfma_f32_16x16x32_bf16(af1, gfrag[tm], zf, 0, 0, 0);
            pf[tm].u[0] = pk2(__builtin_amdgcn_exp2f(s0[0]) * sc0.x,
                              __builtin_amdgcn_exp2f(s0[1]) * sc0.y);
            pf[tm].u[1] = pk2(__builtin_amdgcn_exp2f(s0[2]) * sc0.z,
                              __builtin_amdgcn_exp2f(s0[3]) * sc0.w);
            pf[tm].u[2] = pk2(__builtin_amdgcn_exp2f(s1[0]) * sc1.x,
                              __builtin_amdgcn_exp2f(s1[1]) * sc1.y);
            pf[tm].u[3] = pk2(__builtin_amdgcn_exp2f(s1[2]) * sc1.z,
                              __builtin_amdgcn_exp2f(s1[3]) * sc1.w);
        }

        // PV: acc[c,m] += V[c, sigma(k)] * P[sigma(k), m]  (c-half = ch)
        #pragma unroll
        for (int tc = 0; tc < 4; ++tc) {
            const int cl = 16 * tc + l16;
            const uint2 va  = *reinterpret_cast<const uint2*>(
                Vb + cl * 64 + 8 * (g16 ^ (cl & 6)));
            const uint2 vb2 = *reinterpret_cast<const uint2*>(
                Vb + cl * 64 + 8 * ((4 + g16) ^ (cl & 6)));
            union { uint u[4]; short8v s; } av;
            av.u[0] = va.x;  av.u[1] = va.y;
            av.u[2] = vb2.x; av.u[3] = vb2.y;
            #pragma unroll
            for (int tm = 0; tm < 4; ++tm)
                acc[tc][tm] = __builtin_amdgcn_mfma_f32_16x16x32_bf16(av.s, pf[tm].s, acc[tc][tm], 0, 0, 0);
        }
        bo ^= VBUF;
    }
#undef STAGE

    // ---- epilogue: 3-round cross-nq reduction (staging LDS reused) ----
    float4v* rl = (float4v*)smem;
    __syncthreads();
    if (nq >= 4) {
        const int slot = (nq - 4) * 2 + ch;
        #pragma unroll
        for (int tc = 0; tc < 4; ++tc)
            #pragma unroll
            for (int tm = 0; tm < 4; ++tm)
                rl[(slot * 16 + tc * 4 + tm) * 64 + l] = acc[tc][tm];
    }
    __syncthreads();
    if (nq < 4) {
        const int slot = nq * 2 + ch;
        #pragma unroll
        for (int tc = 0; tc < 4; ++tc)
            #pragma unroll
            for (int tm = 0; tm < 4; ++tm)
                acc[tc][tm] += rl[(slot * 16 + tc * 4 + tm) * 64 + l];
    }
    __syncthreads();
    if (nq == 2 || nq == 3) {
        const int slot = (nq - 2) * 2 + ch;
        #pragma unroll
        for (int tc = 0; tc < 4; ++tc)
            #pragma unroll
            for (int tm = 0; tm < 4; ++tm)
                rl[(slot * 16 + tc * 4 + tm) * 64 + l] = acc[tc][tm];
    }
    __syncthreads();
    if (nq < 2) {
        const int slot = nq * 2 + ch;
        #pragma unroll
        for (int tc = 0; tc < 4; ++tc)
            #pragma unroll
            for (int tm = 0; tm < 4; ++tm)
                acc[tc][tm] += rl[(slot * 16 + tc * 4 + tm) * 64 + l];
    }
    __syncthreads();
    if (nq == 1) {
        #pragma unroll
        for (int tc = 0; tc < 4; ++tc)
            #pragma unroll
            for (int tm = 0; tm < 4; ++tm)
                rl[(ch * 16 + tc * 4 + tm) * 64 + l] = acc[tc][tm];
    }
    __syncthreads();
    if (nq == 0) {
        const float* xb = x   + (size_t)b * CC * NN;
        float*       ob = out + (size_t)b * CC * NN;
        #pragma unroll
        for (int tc = 0; tc < 4; ++tc) {
            #pragma unroll
            for (int tm = 0; tm < 4; ++tm) {
                float4v s = acc[tc][tm] + rl[(ch * 16 + tc * 4 + tm) * 64 + l];
                const int cb = 64 * ch + 16 * tc + 4 * g16;
                const int m  = m0 + 16 * tm + l16;
                #pragma unroll
                for (int r = 0; r < 4; ++r) {
                    const size_t idx = (size_t)(cb + r) * NN + m;
                    ob[idx] = s[r] + xb[idx];
                }
            }
        }
    }
}

// ---------------------------------------------------------------------------
extern "C" void kernel_launch(void* const* d_in, const int* in_sizes, int n_in,
                              void* d_out, int out_size, void* d_ws, size_t ws_size,
                              hipStream_t stream)
{
    const float* x     = (const float*)d_in[0];
    const float* Wf    = (const float*)d_in[1];
    const float* bf    = (const float*)d_in[2];
    const float* Wg    = (const float*)d_in[3];
    const float* bg    = (const float*)d_in[4];
    const float* Wh    = (const float*)d_in[5];
    const float* bh    = (const float*)d_in[6];
    const float* gamma = (const float*)d_in[7];

    ushort* ft = (ushort*)d_ws;                    // [B][N][CK] bf16 (x log2e)
    ushort* gt = ft + (size_t)BB * NN * CK;        // [B][N][CK] bf16
    ushort* vh = gt + (size_t)BB * NN * CK;        // [B][C][N]  bf16 (sign folded)
    float* Dpart = (float*)(vh + (size_t)BB * CC * NN);  // [B*N][8]
    float* sc    = Dpart + (size_t)BB * NN * 8;          // [B*N] |g|/D
    float* bias_cat = sc + (size_t)BB * NN;              // [192]
    ushort* Wcat = (ushort*)(bias_cat + 192);            // [192][128] bf16

    float* out = (float*)d_out;

    wprep_kernel<<<dim3(48), 512, 0, stream>>>(Wf, bf, Wg, bg, Wh, bh, gamma, Wcat, bias_cat);
    proj_kernel<<<dim3(NN / 32, BB), 512, 0, stream>>>(x, Wcat, bias_cat, ft, gt, vh);
    pass1_kernel<<<dim3(NN / 64, BB, 8), 256, 0, stream>>>(ft, gt, Dpart);
    reduce_kernel<<<dim3(BB * NN / 256), 256, 0, stream>>>(Dpart, sc, gamma);
    pass2_kernel<<<dim3(256), 1024, 0, stream>>>(ft, gt, vh, sc, x, out);
}

// Round 24
// 82.412 us; speedup vs baseline: 1.1656x; 1.0686x over previous
//
#include <hip/hip_runtime.h>
#include <hip/hip_bf16.h>

#define BB 4
#define CC 128
#define NN 4096
#define CK 32
#define L2E 1.442695040888963f

typedef __attribute__((ext_vector_type(8))) short short8v;
typedef __attribute__((ext_vector_type(4))) float float4v;

__device__ inline ushort f2bf(float f) {
    union { __hip_bfloat16 h; ushort u; } cv;
    cv.h = __float2bfloat16(f);
    return cv.u;
}
__device__ inline float bf2f(ushort u) {
    union { uint u; float f; } cv;
    cv.u = ((uint)u) << 16;
    return cv.f;
}
__device__ inline uint pk2(float lo, float hi) {
    return ((uint)f2bf(lo)) | ((uint)f2bf(hi) << 16);
}
__device__ __forceinline__ void gll16(const void* g, void* l) {
    __builtin_amdgcn_global_load_lds(
        (const __attribute__((address_space(1))) void*)g,
        (__attribute__((address_space(3))) void*)l, 16, 0, 0);
}

// ---------------------------------------------------------------------------
// Kernel 0: weight prep.  Wcat[192][128] bf16 = {Wf*L2E; Wg; Wh*sgn},
// bias[192] fp32 = {bf*L2E; bg; bh*sgn}.
// ---------------------------------------------------------------------------
__global__ __launch_bounds__(512) void wprep_kernel(
    const float* __restrict__ Wf, const float* __restrict__ bf,
    const float* __restrict__ Wg, const float* __restrict__ bg,
    const float* __restrict__ Wh, const float* __restrict__ bh,
    const float* __restrict__ gamma,
    ushort* __restrict__ Wcat, float* __restrict__ bias_cat)
{
    const float sgn = (gamma[0] < 0.f) ? -1.f : 1.f;
    const int t = blockIdx.x * 512 + threadIdx.x;   // 0..24575
    const int o = t >> 7, c = t & 127;
    float w, scale;
    if (o < 32)      { w = Wf[o * 128 + c];        scale = L2E;  }
    else if (o < 64) { w = Wg[(o - 32) * 128 + c]; scale = 1.f;  }
    else             { w = Wh[(o - 64) * 128 + c]; scale = sgn;  }
    Wcat[t] = f2bf(w * scale);
    if (t < 192) {
        const float bv = (t < 32) ? bf[t] * L2E
                       : (t < 64) ? bg[t - 32]
                                  : bh[t - 64] * sgn;
        bias_cat[t] = bv;
    }
}

// ---------------------------------------------------------------------------
// Kernel 1: MFMA projections.  Grid (N/32, B) = 512 blocks, 512 thr.
// ---------------------------------------------------------------------------
__global__ __launch_bounds__(512) void proj_kernel(
    const float* __restrict__ x, const ushort* __restrict__ Wcat,
    const float* __restrict__ bias_cat,
    ushort* __restrict__ ft, ushort* __restrict__ gt, ushort* __restrict__ vh)
{
    __shared__ ushort xs[32][132];
    const int t  = threadIdx.x;
    const int n0 = blockIdx.x * 32;
    const int b  = blockIdx.y;
    const float* xb = x + (size_t)b * CC * NN;

    {
        const int nl = t & 31, cg = t >> 5;
        #pragma unroll
        for (int i = 0; i < 8; ++i) {
            const int c = cg + 16 * i;
            xs[nl][c] = f2bf(xb[(size_t)c * NN + n0 + nl]);
        }
    }
    __syncthreads();

    const int w   = t >> 6;
    const int l   = t & 63;
    const int g16 = l >> 4;
    const int l16 = l & 15;
    const int og  = w >> 1;
    const int nh  = w & 1;

    const float4v zf = {0.f, 0.f, 0.f, 0.f};
    float4v acc[3];
    #pragma unroll
    for (int tt = 0; tt < 3; ++tt) acc[tt] = zf;

    #pragma unroll
    for (int kt = 0; kt < 4; ++kt) {
        const short8v bfr = *reinterpret_cast<const short8v*>(
            &xs[nh * 16 + l16][32 * kt + 8 * g16]);
        #pragma unroll
        for (int tt = 0; tt < 3; ++tt) {
            const short8v afr = *reinterpret_cast<const short8v*>(
                &Wcat[(size_t)(48 * og + 16 * tt + l16) * 128 + 32 * kt + 8 * g16]);
            acc[tt] = __builtin_amdgcn_mfma_f32_16x16x32_bf16(afr, bfr, acc[tt], 0, 0, 0);
        }
    }

    const int n = n0 + nh * 16 + l16;
    #pragma unroll
    for (int tt = 0; tt < 3; ++tt) {
        const int ob = 48 * og + 16 * tt + 4 * g16;
        const float4 b4 = *reinterpret_cast<const float4*>(&bias_cat[ob]);
        const float v0 = acc[tt][0] + b4.x;
        const float v1 = acc[tt][1] + b4.y;
        const float v2 = acc[tt][2] + b4.z;
        const float v3 = acc[tt][3] + b4.w;
        if (ob < 32) {
            ushort4 pk;
            pk.x = f2bf(v0); pk.y = f2bf(v1); pk.z = f2bf(v2); pk.w = f2bf(v3);
            *reinterpret_cast<ushort4*>(&ft[((size_t)b * NN + n) * CK + ob]) = pk;
        } else if (ob < 64) {
            ushort4 pk;
            pk.x = f2bf(v0); pk.y = f2bf(v1); pk.z = f2bf(v2); pk.w = f2bf(v3);
            *reinterpret_cast<ushort4*>(&gt[((size_t)b * NN + n) * CK + (ob - 32)]) = pk;
        } else {
            const int c = ob - 64;
            vh[((size_t)b * CC + c + 0) * NN + n] = f2bf(v0);
            vh[((size_t)b * CC + c + 1) * NN + n] = f2bf(v1);
            vh[((size_t)b * CC + c + 2) * NN + n] = f2bf(v2);
            vh[((size_t)b * CC + c + 3) * NN + n] = f2bf(v3);
        }
    }
}

// ---------------------------------------------------------------------------
// Kernel 2: partial denominators D = sum_m 2^(S~) via MFMA.
// ---------------------------------------------------------------------------
__global__ __launch_bounds__(256) void pass1_kernel(
    const ushort* __restrict__ ft, const ushort* __restrict__ gt,
    float* __restrict__ Dpart)
{
    const int t   = threadIdx.x;
    const int w   = t >> 6;
    const int l   = t & 63;
    const int g16 = l >> 4;
    const int l16 = l & 15;
    const int n0  = blockIdx.x * 64;
    const int b   = blockIdx.y;
    const int mz  = blockIdx.z;

    const ushort* ftb = ft + (size_t)b * NN * CK;
    const ushort* gtb = gt + (size_t)b * NN * CK;

    const short8v afrag = *reinterpret_cast<const short8v*>(
        &ftb[(size_t)(n0 + 16 * w + l16) * CK + 8 * g16]);

    const float4v zf = {0.f, 0.f, 0.f, 0.f};
    float d0 = 0.f, d1 = 0.f, d2 = 0.f, d3 = 0.f;
    const int m0 = mz * 512;

    short8v bfA = *reinterpret_cast<const short8v*>(
        &gtb[(size_t)(m0 + l16) * CK + 8 * g16]);
    #pragma unroll 1
    for (int mt = 0; mt < 32; mt += 2) {
        const short8v bfB = *reinterpret_cast<const short8v*>(
            &gtb[(size_t)(m0 + (mt + 1) * 16 + l16) * CK + 8 * g16]);
        float4v s = __builtin_amdgcn_mfma_f32_16x16x32_bf16(afrag, bfA, zf, 0, 0, 0);
        d0 += __builtin_amdgcn_exp2f(s[0]); d1 += __builtin_amdgcn_exp2f(s[1]);
        d2 += __builtin_amdgcn_exp2f(s[2]); d3 += __builtin_amdgcn_exp2f(s[3]);
        bfA = *reinterpret_cast<const short8v*>(
            &gtb[(size_t)(m0 + (((mt + 2) & 31)) * 16 + l16) * CK + 8 * g16]);
        float4v s2 = __builtin_amdgcn_mfma_f32_16x16x32_bf16(afrag, bfB, zf, 0, 0, 0);
        d0 += __builtin_amdgcn_exp2f(s2[0]); d1 += __builtin_amdgcn_exp2f(s2[1]);
        d2 += __builtin_amdgcn_exp2f(s2[2]); d3 += __builtin_amdgcn_exp2f(s2[3]);
    }
    #pragma unroll
    for (int msk = 1; msk <= 8; msk <<= 1) {
        d0 += __shfl_xor(d0, msk);
        d1 += __shfl_xor(d1, msk);
        d2 += __shfl_xor(d2, msk);
        d3 += __shfl_xor(d3, msk);
    }
    if (l16 < 4) {
        const int n = n0 + 16 * w + 4 * g16 + l16;
        const float v = (l16 == 0) ? d0 : (l16 == 1) ? d1 : (l16 == 2) ? d2 : d3;
        Dpart[((size_t)b * NN + n) * 8 + mz] = v;
    }
}

// ---------------------------------------------------------------------------
// Kernel 3: sc[n] = |gamma| / D[n]
// ---------------------------------------------------------------------------
__global__ __launch_bounds__(256) void reduce_kernel(
    const float* __restrict__ Dpart, float* __restrict__ sc,
    const float* __restrict__ gamma)
{
    const int i = blockIdx.x * 256 + threadIdx.x;
    const float4 a4 = *reinterpret_cast<const float4*>(&Dpart[(size_t)i * 8]);
    const float4 b4 = *reinterpret_cast<const float4*>(&Dpart[(size_t)i * 8 + 4]);
    const float D = (a4.x + a4.y + a4.z + a4.w) + (b4.x + b4.y + b4.z + b4.w);
    sc[i] = fabsf(gamma[0]) / D;
}

// ---------------------------------------------------------------------------
// Kernel 3b: vh[b][c][n] *= sc[b*N + n]
// ---------------------------------------------------------------------------
__global__ __launch_bounds__(256) void vscale_kernel(
    ushort* __restrict__ vh, const float* __restrict__ sc)
{
    const size_t i8   = (size_t)blockIdx.x * 256 + threadIdx.x;
    const size_t base = i8 * 8;
    const int    n    = (int)(base & (NN - 1));
    const int    b    = (int)(base / ((size_t)CC * NN));

    ushort4 v0 = *reinterpret_cast<const ushort4*>(&vh[base]);
    ushort4 v1 = *reinterpret_cast<const ushort4*>(&vh[base + 4]);
    const float4 s0 = *reinterpret_cast<const float4*>(&sc[(size_t)b * NN + n]);
    const float4 s1 = *reinterpret_cast<const float4*>(&sc[(size_t)b * NN + n + 4]);

    v0.x = f2bf(bf2f(v0.x) * s0.x);
    v0.y = f2bf(bf2f(v0.y) * s0.y);
    v0.z = f2bf(bf2f(v0.z) * s0.z);
    v0.w = f2bf(bf2f(v0.w) * s0.w);
    v1.x = f2bf(bf2f(v1.x) * s1.x);
    v1.y = f2bf(bf2f(v1.y) * s1.y);
    v1.z = f2bf(bf2f(v1.z) * s1.z);
    v1.w = f2bf(bf2f(v1.w) * s1.w);

    *reinterpret_cast<ushort4*>(&vh[base])     = v0;
    *reinterpret_cast<ushort4*>(&vh[base + 4]) = v1;
}

// ---------------------------------------------------------------------------
// Kernel 4 (r16/r19 PROVEN): sigma-permuted PV.  BM=64, grid 256 (1 block/CU),
// 1024 thr = 16 waves = (ch in 2, nq in 8) -> 4 waves/SIMD.  V staged
// wave-private dbuf (64c x 32n) via 4 x gll16/step; af direct loads issued
// before STAGE; counted vmcnt(4); zero barriers in main loop.
// P = exp2(S~) direct (scales folded into ft and vh).
// ---------------------------------------------------------------------------
#define WSTR  8192
#define VBUF  4096

__global__ __launch_bounds__(1024) void pass2_kernel(
    const ushort* __restrict__ ft, const ushort* __restrict__ gt,
    const ushort* __restrict__ vh,
    const float* __restrict__ x, float* __restrict__ out)
{
    __shared__ __align__(16) char smem[16 * WSTR];   // 128 KB

    const int t   = threadIdx.x;
    const int w   = t >> 6;
    const int l   = t & 63;
    const int g16 = l >> 4;
    const int l16 = l & 15;
    const int ch  = w & 1;     // c-half
    const int nq  = w >> 1;    // n-eighth (0..7)

    const int bid = blockIdx.x;
    const int xcd = bid & 7;
    const int b   = xcd >> 1;
    const int m0  = ((bid >> 3) + 32 * (xcd & 1)) * 64;

    const ushort* ftb = ft + (size_t)b * NN * CK;
    const ushort* gtb = gt + (size_t)b * NN * CK;
    const ushort* vhb = vh + (size_t)b * CC * NN;

    char* wsm = smem + w * WSTR;

    short8v gfrag[4];
    #pragma unroll
    for (int tm = 0; tm < 4; ++tm)
        gfrag[tm] = *reinterpret_cast<const short8v*>(
            &gtb[(size_t)(m0 + 16 * tm + l16) * CK + 8 * g16]);

    const float4v zf = {0.f, 0.f, 0.f, 0.f};
    float4v acc[4][4];   // [tc][tm]
    #pragma unroll
    for (int tc = 0; tc < 4; ++tc)
        #pragma unroll
        for (int tm = 0; tm < 4; ++tm) acc[tc][tm] = zf;

    const int nbase = nq * 512;
    const int rr = l >> 2, cp = l & 3;

#define STAGE(n0_, bo_) do {                                                   \
    _Pragma("unroll")                                                          \
    for (int j = 0; j < 4; ++j) {                                              \
        const int row = j * 16 + rr;                                           \
        gll16(vhb + (size_t)(64 * ch + row) * NN + (n0_)                       \
                  + (((2 * cp) ^ (row & 6)) << 2),                             \
              wsm + (bo_) + j * 1024);                                         \
    }                                                                          \
} while (0)

    // prologue: stage step 0, drain everything (incl. gfrag loads)
    STAGE(nbase, 0);
    asm volatile("s_waitcnt vmcnt(0)" ::: "memory");

    int bo = 0;
    #pragma unroll 1
    for (int st = 0; st < 16; ++st) {
        const int n0 = nbase + st * 32;

        // af loads for this step (their drain rides the vmcnt below)
        const short8v af0 = *reinterpret_cast<const short8v*>(
            &ftb[(size_t)(n0 + l16) * CK + 8 * g16]);
        const short8v af1 = *reinterpret_cast<const short8v*>(
            &ftb[(size_t)(n0 + 16 + l16) * CK + 8 * g16]);

        if (st < 15) {
            STAGE(n0 + 32, bo ^ VBUF);
            asm volatile("s_waitcnt vmcnt(4)" ::: "memory");
        } else {
            asm volatile("s_waitcnt vmcnt(0)" ::: "memory");
        }

        const char* Vb = wsm + bo;

        // S~ = (F*log2e)^T G over 64m x 32n; P = exp2(S~) -> PV B-frags
        union { uint u[4]; short8v s; } pf[4];
        #pragma unroll
        for (int tm = 0; tm < 4; ++tm) {
            float4v s0 = __builtin_amdgcn_mfma_f32_16x16x32_bf16(af0, gfrag[tm], zf, 0, 0, 0);
            float4v s1 = __builtin_amdgcn_mfma_f32_16x16x32_bf16(af1, gfrag[tm], zf, 0, 0, 0);
            pf[tm].u[0] = pk2(__builtin_amdgcn_exp2f(s0[0]), __builtin_amdgcn_exp2f(s0[1]));
            pf[tm].u[1] = pk2(__builtin_amdgcn_exp2f(s0[2]), __builtin_amdgcn_exp2f(s0[3]));
            pf[tm].u[2] = pk2(__builtin_amdgcn_exp2f(s1[0]), __builtin_amdgcn_exp2f(s1[1]));
            pf[tm].u[3] = pk2(__builtin_amdgcn_exp2f(s1[2]), __builtin_amdgcn_exp2f(s1[3]));
        }

        // PV: acc[c,m] += V[c, sigma(k)] * P[sigma(k), m]  (c-half = ch)
        #pragma unroll
        for (int tc = 0; tc < 4; ++tc) {
            const int cl = 16 * tc + l16;
            const uint2 va  = *reinterpret_cast<const uint2*>(
                Vb + cl * 64 + 8 * (g16 ^ (cl & 6)));
            const uint2 vb2 = *reinterpret_cast<const uint2*>(
                Vb + cl * 64 + 8 * ((4 + g16) ^ (cl & 6)));
            union { uint u[4]; short8v s; } av;
            av.u[0] = va.x;  av.u[1] = va.y;
            av.u[2] = vb2.x; av.u[3] = vb2.y;
            #pragma unroll
            for (int tm = 0; tm < 4; ++tm)
                acc[tc][tm] = __builtin_amdgcn_mfma_f32_16x16x32_bf16(av.s, pf[tm].s, acc[tc][tm], 0, 0, 0);
        }
        bo ^= VBUF;
    }
#undef STAGE

    // ---- epilogue: 3-round cross-nq reduction (staging LDS reused) ----
    float4v* rl = (float4v*)smem;
    __syncthreads();
    if (nq >= 4) {
        const int slot = (nq - 4) * 2 + ch;
        #pragma unroll
        for (int tc = 0; tc < 4; ++tc)
            #pragma unroll
            for (int tm = 0; tm < 4; ++tm)
                rl[(slot * 16 + tc * 4 + tm) * 64 + l] = acc[tc][tm];
    }
    __syncthreads();
    if (nq < 4) {
        const int slot = nq * 2 + ch;
        #pragma unroll
        for (int tc = 0; tc < 4; ++tc)
            #pragma unroll
            for (int tm = 0; tm < 4; ++tm)
                acc[tc][tm] += rl[(slot * 16 + tc * 4 + tm) * 64 + l];
    }
    __syncthreads();
    if (nq == 2 || nq == 3) {
        const int slot = (nq - 2) * 2 + ch;
        #pragma unroll
        for (int tc = 0; tc < 4; ++tc)
            #pragma unroll
            for (int tm = 0; tm < 4; ++tm)
                rl[(slot * 16 + tc * 4 + tm) * 64 + l] = acc[tc][tm];
    }
    __syncthreads();
    if (nq < 2) {
        const int slot = nq * 2 + ch;
        #pragma unroll
        for (int tc = 0; tc < 4; ++tc)
            #pragma unroll
            for (int tm = 0; tm < 4; ++tm)
                acc[tc][tm] += rl[(slot * 16 + tc * 4 + tm) * 64 + l];
    }
    __syncthreads();
    if (nq == 1) {
        #pragma unroll
        for (int tc = 0; tc < 4; ++tc)
            #pragma unroll
            for (int tm = 0; tm < 4; ++tm)
                rl[(ch * 16 + tc * 4 + tm) * 64 + l] = acc[tc][tm];
    }
    __syncthreads();
    if (nq == 0) {
        const float* xb = x   + (size_t)b * CC * NN;
        float*       ob = out + (size_t)b * CC * NN;
        #pragma unroll
        for (int tc = 0; tc < 4; ++tc) {
            #pragma unroll
            for (int tm = 0; tm < 4; ++tm) {
                float4v s = acc[tc][tm] + rl[(ch * 16 + tc * 4 + tm) * 64 + l];
                const int cb = 64 * ch + 16 * tc + 4 * g16;
                const int m  = m0 + 16 * tm + l16;
                #pragma unroll
                for (int r = 0; r < 4; ++r) {
                    const size_t idx = (size_t)(cb + r) * NN + m;
                    ob[idx] = s[r] + xb[idx];
                }
            }
        }
    }
}

// ---------------------------------------------------------------------------
extern "C" void kernel_launch(void* const* d_in, const int* in_sizes, int n_in,
                              void* d_out, int out_size, void* d_ws, size_t ws_size,
                              hipStream_t stream)
{
    const float* x     = (const float*)d_in[0];
    const float* Wf    = (const float*)d_in[1];
    const float* bf    = (const float*)d_in[2];
    const float* Wg    = (const float*)d_in[3];
    const float* bg    = (const float*)d_in[4];
    const float* Wh    = (const float*)d_in[5];
    const float* bh    = (const float*)d_in[6];
    const float* gamma = (const float*)d_in[7];

    ushort* ft = (ushort*)d_ws;                    // [B][N][CK] bf16 (x log2e)
    ushort* gt = ft + (size_t)BB * NN * CK;        // [B][N][CK] bf16
    ushort* vh = gt + (size_t)BB * NN * CK;        // [B][C][N]  bf16 (sign folded)
    float* Dpart = (float*)(vh + (size_t)BB * CC * NN);  // [B*N][8]
    float* sc    = Dpart + (size_t)BB * NN * 8;          // [B*N] |g|/D
    float* bias_cat = sc + (size_t)BB * NN;              // [192]
    ushort* Wcat = (ushort*)(bias_cat + 192);            // [192][128] bf16

    float* out = (float*)d_out;

    wprep_kernel<<<dim3(48), 512, 0, stream>>>(Wf, bf, Wg, bg, Wh, bh, gamma, Wcat, bias_cat);
    proj_kernel<<<dim3(NN / 32, BB), 512, 0, stream>>>(x, Wcat, bias_cat, ft, gt, vh);
    pass1_kernel<<<dim3(NN / 64, BB, 8), 256, 0, stream>>>(ft, gt, Dpart);
    reduce_kernel<<<dim3(BB * NN / 256), 256, 0, stream>>>(Dpart, sc, gamma);
    vscale_kernel<<<dim3(BB * CC * NN / 8 / 256), 256, 0, stream>>>(vh, sc);
    pass2_kernel<<<dim3(256), 1024, 0, stream>>>(ft, gt, vh, x, out);
}